// Round 5
// baseline (298.436 us; speedup 1.0000x reference)
//
#include <hip/hip_runtime.h>

#define D_IN 128
#define H1P 136            // padded LDS pitch for h1 tile (bf16 elems)

#if defined(__has_builtin)
#if __has_builtin(__builtin_amdgcn_cvt_pk_f32_fp8)
#define HAVE_FP8 1
#endif
#endif
#ifndef HAVE_FP8
#define HAVE_FP8 0
#endif

typedef unsigned short u16;
typedef unsigned char u8;
typedef __attribute__((ext_vector_type(8))) short short8;
typedef __attribute__((ext_vector_type(4))) float f32x4;
typedef __attribute__((ext_vector_type(2))) float f32x2;

static inline size_t align_up(size_t v, size_t a) { return (v + a - 1) & ~(a - 1); }

__device__ inline u16 f2bf(float f) {
    union { float f; unsigned int u; } c; c.f = f;
    unsigned int u = c.u;
    return (u16)((u + 0x7fffu + ((u >> 16) & 1u)) >> 16);   // RNE
}
__device__ inline unsigned int packbf2(float lo, float hi) {
    return (unsigned int)f2bf(lo) | ((unsigned int)f2bf(hi) << 16);
}
__device__ inline f32x2 bf2f2(unsigned int u) {
    union { unsigned int u; float f; } lo, hi;
    lo.u = u << 16;
    hi.u = u & 0xffff0000u;
    f32x2 r; r.x = lo.f; r.y = hi.f;
    return r;
}
// f32 -> OCP e4m3fn (RNE, saturate to 448, denormal-correct)
__device__ inline unsigned int f2fp8(float f) {
    float m = fabsf(f);
    m = fminf(m, 448.0f);
    unsigned int s = (__float_as_uint(f) >> 31) << 7;
    if (m < 0.015625f) {                       // < 2^-6 : denormal codes 0..7 (and 8 on round-up)
        int c = (int)rintf(m * 512.0f);
        return s | (unsigned int)c;
    }
    unsigned int au = __float_as_uint(m);
    au += 0x7FFFF + ((au >> 20) & 1);          // RNE to 3 mantissa bits
    int e = (int)(au >> 23) - 127;
    int mant = (int)(au >> 20) & 7;
    int code = ((e + 7) << 3) | mant;
    if (code > 0x7E) code = 0x7E;              // clamp to 448
    return s | (unsigned int)code;
}
// 2 packed OCP e4m3fn -> f32x2; HI selects bytes 2,3 vs 0,1 (compile-time constant!)
template <bool HI>
__device__ inline f32x2 cvt2(unsigned int w) {
#if HAVE_FP8
    return __builtin_amdgcn_cvt_pk_f32_fp8(w, HI);
#else
    unsigned int b0 = (w >> (HI ? 16 : 0)) & 0xff;
    unsigned int b1 = (w >> (HI ? 24 : 8)) & 0xff;
    float v0, v1;
    {
        int e = (b0 >> 3) & 0xF, m = b0 & 7;
        v0 = e ? __builtin_ldexpf((float)(8 + m), e - 10) : __builtin_ldexpf((float)m, -9);
        if (b0 & 0x80) v0 = -v0;
    }
    {
        int e = (b1 >> 3) & 0xF, m = b1 & 7;
        v1 = e ? __builtin_ldexpf((float)(8 + m), e - 10) : __builtin_ldexpf((float)m, -9);
        if (b1 & 0x80) v1 = -v1;
    }
    f32x2 r; r.x = v0; r.y = v1;
    return r;
#endif
}

#define GLDS16(gp, lp) \
    __builtin_amdgcn_global_load_lds((const __attribute__((address_space(1))) void*)(gp), \
                                     (__attribute__((address_space(3))) void*)(lp), 16, 0, 0)

// ---------------- prep: cast x->bf16 + x->fp8 + pack weights + node-level degree count ----------
__global__ void k_prep(const float* __restrict__ x, u16* __restrict__ xb,
                       unsigned int* __restrict__ xf8, int total4,
                       const float* __restrict__ Ws1, const float* __restrict__ Wn1,
                       const float* __restrict__ Ws2, const float* __restrict__ Wn2,
                       u16* __restrict__ W1t, u16* __restrict__ W2t,
                       const int* __restrict__ dst, int* __restrict__ deg, int e) {
    int i = blockIdx.x * blockDim.x + threadIdx.x;
    if (i < total4) {
        float4 v = ((const float4*)x)[i];
        uint2 o;
        o.x = packbf2(v.x, v.y);
        o.y = packbf2(v.z, v.w);
        *(uint2*)&xb[(size_t)i * 4] = o;
        xf8[i] = f2fp8(v.x) | (f2fp8(v.y) << 8) | (f2fp8(v.z) << 16) | (f2fp8(v.w) << 24);
    }
    if (i < 128 * 256) {
        int nn = i >> 8, kk = i & 255;
        float v = (kk < 128) ? Ws1[kk * 128 + nn] : Wn1[(kk - 128) * 128 + nn];
        W1t[i] = f2bf(v);
    }
    if (i < 128 * 128) {
        int nn = i >> 7, kk = i & 127;
        float v = (nn < 64) ? Ws2[kk * 64 + nn] : Wn2[kk * 64 + (nn - 64)];
        W2t[i] = f2bf(v);
    }
    // per-node in-degree (deg[] pre-zeroed; 400 KB -> L2-resident atomics)
    if (i < e)
        atomicAdd(&deg[dst[i]], 1);
}

// ---------------- scan 1: per-block (1024) exclusive scan in place + block sums ----------------
__global__ void k_scan1(int* __restrict__ a, int* __restrict__ bsum, int T) {
    __shared__ int sd[256];
    int t = threadIdx.x;
    int base = blockIdx.x * 1024 + t * 4;
    int v[4]; int s = 0;
    #pragma unroll
    for (int j = 0; j < 4; ++j) { v[j] = (base + j < T) ? a[base + j] : 0; s += v[j]; }
    sd[t] = s;
    __syncthreads();
    #pragma unroll
    for (int off = 1; off < 256; off <<= 1) {
        int x = (t >= off) ? sd[t - off] : 0;
        __syncthreads();
        sd[t] += x;
        __syncthreads();
    }
    int run = sd[t] - s;
    #pragma unroll
    for (int j = 0; j < 4; ++j) {
        if (base + j < T) a[base + j] = run;
        run += v[j];
    }
    if (t == 255) bsum[blockIdx.x] = sd[255];
}

// ---------------- rs finalize: add block-sum scan, emit row starts + cursor copy ----------------
__global__ void k_rs(const int* __restrict__ dscan, const int* __restrict__ bsum,
                     int* __restrict__ rs, int* __restrict__ cur, int n, int e, int nblk) {
    __shared__ int bscan[128];
    int t = threadIdx.x;
    int own = 0;
    if (t < 128) {
        own = (t < nblk) ? bsum[t] : 0;
        bscan[t] = own;
    }
    __syncthreads();
    #pragma unroll
    for (int off = 1; off < 128; off <<= 1) {
        int v = (t < 128 && t >= off) ? bscan[t - off] : 0;
        __syncthreads();
        if (t < 128) bscan[t] += v;
        __syncthreads();
    }
    if (t < 128) bscan[t] -= own;   // exclusive
    __syncthreads();
    int i = blockIdx.x * blockDim.x + t;
    if (i < n) {
        int r = dscan[i] + bscan[i >> 10];
        rs[i] = r;
        cur[i] = r;
    }
    if (i == 0) rs[n] = e;
}

// ---------------- place: direct CSR scatter via per-node atomic cursors ----------------
__global__ void k_place(const int* __restrict__ src, const int* __restrict__ dst,
                        int* __restrict__ cur, int* __restrict__ csr, int e) {
    int i = blockIdx.x * blockDim.x + threadIdx.x;
    if (i < e) {
        int p = atomicAdd(&cur[dst[i]], 1);
        csr[p] = src[i];
    }
}

#define ACC8(U) do { \
    a0 += cvt2<false>((U).x); a1 += cvt2<true>((U).x);  \
    a2 += cvt2<false>((U).y); a3 += cvt2<true>((U).y);  \
    a4 += cvt2<false>((U).z); a5 += cvt2<true>((U).z);  \
    a6 += cvt2<false>((U).w); a7 += cvt2<true>((U).w); } while (0)

// ---------------- layer-1 gather-aggregate: 8 lanes per node, group-serial, NO reduce ----------
// Each lane owns a private 16 B (16 fp8 feats) slice of the row; the 8-lane group walks its
// node's edge list (unroll-8 => up to 64 row-gathers in flight per wave). Zero cross-lane traffic.
__global__ void k_agg1(const u8* __restrict__ xf8, const u16* __restrict__ xb,
                       const int* __restrict__ rs, const int* __restrict__ csr,
                       u16* __restrict__ hnb, int n) {
    int g = (blockIdx.x * blockDim.x + threadIdx.x) >> 3;   // node index
    int l8 = threadIdx.x & 7;                               // 16 B feature slice
    if (g >= n) return;
    int start = rs[g];
    int deg = rs[g + 1] - start;
    float inv = 1.0f / (1.0f + (float)deg);
    const int* nb = csr + start;
    const u8* base = xf8 + l8 * 16;
    f32x2 a0 = {0.f,0.f}, a1 = {0.f,0.f}, a2 = {0.f,0.f}, a3 = {0.f,0.f};
    f32x2 a4 = {0.f,0.f}, a5 = {0.f,0.f}, a6 = {0.f,0.f}, a7 = {0.f,0.f};
    int k = 0;
    for (; k + 7 < deg; k += 8) {
        int s0 = nb[k],     s1 = nb[k + 1], s2 = nb[k + 2], s3 = nb[k + 3];
        int s4 = nb[k + 4], s5 = nb[k + 5], s6 = nb[k + 6], s7 = nb[k + 7];
        uint4 u0 = *(const uint4*)(base + (size_t)s0 * 128);
        uint4 u1 = *(const uint4*)(base + (size_t)s1 * 128);
        uint4 u2 = *(const uint4*)(base + (size_t)s2 * 128);
        uint4 u3 = *(const uint4*)(base + (size_t)s3 * 128);
        uint4 u4 = *(const uint4*)(base + (size_t)s4 * 128);
        uint4 u5 = *(const uint4*)(base + (size_t)s5 * 128);
        uint4 u6 = *(const uint4*)(base + (size_t)s6 * 128);
        uint4 u7 = *(const uint4*)(base + (size_t)s7 * 128);
        ACC8(u0); ACC8(u1); ACC8(u2); ACC8(u3);
        ACC8(u4); ACC8(u5); ACC8(u6); ACC8(u7);
    }
    for (; k + 3 < deg; k += 4) {
        int s0 = nb[k], s1 = nb[k + 1], s2 = nb[k + 2], s3 = nb[k + 3];
        uint4 u0 = *(const uint4*)(base + (size_t)s0 * 128);
        uint4 u1 = *(const uint4*)(base + (size_t)s1 * 128);
        uint4 u2 = *(const uint4*)(base + (size_t)s2 * 128);
        uint4 u3 = *(const uint4*)(base + (size_t)s3 * 128);
        ACC8(u0); ACC8(u1); ACC8(u2); ACC8(u3);
    }
    for (; k < deg; ++k) {
        int s = nb[k];
        uint4 u = *(const uint4*)(base + (size_t)s * 128);
        ACC8(u);
    }
    // self row (bf16): feats [l8*16, l8*16+16)
    uint4 s0 = *(const uint4*)(xb + (size_t)g * 128 + l8 * 16);
    uint4 s1 = *(const uint4*)(xb + (size_t)g * 128 + l8 * 16 + 8);
    a0 += bf2f2(s0.x); a1 += bf2f2(s0.y); a2 += bf2f2(s0.z); a3 += bf2f2(s0.w);
    a4 += bf2f2(s1.x); a5 += bf2f2(s1.y); a6 += bf2f2(s1.z); a7 += bf2f2(s1.w);
    uint4 o0, o1;
    o0.x = packbf2(a0.x * inv, a0.y * inv);
    o0.y = packbf2(a1.x * inv, a1.y * inv);
    o0.z = packbf2(a2.x * inv, a2.y * inv);
    o0.w = packbf2(a3.x * inv, a3.y * inv);
    o1.x = packbf2(a4.x * inv, a4.y * inv);
    o1.y = packbf2(a5.x * inv, a5.y * inv);
    o1.z = packbf2(a6.x * inv, a6.y * inv);
    o1.w = packbf2(a7.x * inv, a7.y * inv);
    *(uint4*)(hnb + (size_t)g * 128 + l8 * 16) = o0;
    *(uint4*)(hnb + (size_t)g * 128 + l8 * 16 + 8) = o1;
}

// ---------------- layer-2 gather-aggregate + epilogue: 8 lanes per node, NO reduce ------------
__global__ void k_agg2(const u16* __restrict__ qp, const int* __restrict__ rs,
                       const int* __restrict__ csr, const float* __restrict__ b2,
                       float* __restrict__ out, int n) {
    int g = (blockIdx.x * blockDim.x + threadIdx.x) >> 3;
    int l8 = threadIdx.x & 7;         // 8 bf16 feats (16 B) of the p-half
    if (g >= n) return;
    int start = rs[g];
    int deg = rs[g + 1] - start;
    float inv = 1.0f / (1.0f + (float)deg);
    const int* nb = csr + start;
    const u16* basep = qp + 64 + l8 * 8;
    f32x2 a0 = {0.f,0.f}, a1 = {0.f,0.f}, a2 = {0.f,0.f}, a3 = {0.f,0.f};
    int k = 0;
    for (; k + 7 < deg; k += 8) {
        int s0 = nb[k],     s1 = nb[k + 1], s2 = nb[k + 2], s3 = nb[k + 3];
        int s4 = nb[k + 4], s5 = nb[k + 5], s6 = nb[k + 6], s7 = nb[k + 7];
        uint4 u0 = *(const uint4*)(basep + (size_t)s0 * 128);
        uint4 u1 = *(const uint4*)(basep + (size_t)s1 * 128);
        uint4 u2 = *(const uint4*)(basep + (size_t)s2 * 128);
        uint4 u3 = *(const uint4*)(basep + (size_t)s3 * 128);
        uint4 u4 = *(const uint4*)(basep + (size_t)s4 * 128);
        uint4 u5 = *(const uint4*)(basep + (size_t)s5 * 128);
        uint4 u6 = *(const uint4*)(basep + (size_t)s6 * 128);
        uint4 u7 = *(const uint4*)(basep + (size_t)s7 * 128);
        a0 += bf2f2(u0.x); a1 += bf2f2(u0.y); a2 += bf2f2(u0.z); a3 += bf2f2(u0.w);
        a0 += bf2f2(u1.x); a1 += bf2f2(u1.y); a2 += bf2f2(u1.z); a3 += bf2f2(u1.w);
        a0 += bf2f2(u2.x); a1 += bf2f2(u2.y); a2 += bf2f2(u2.z); a3 += bf2f2(u2.w);
        a0 += bf2f2(u3.x); a1 += bf2f2(u3.y); a2 += bf2f2(u3.z); a3 += bf2f2(u3.w);
        a0 += bf2f2(u4.x); a1 += bf2f2(u4.y); a2 += bf2f2(u4.z); a3 += bf2f2(u4.w);
        a0 += bf2f2(u5.x); a1 += bf2f2(u5.y); a2 += bf2f2(u5.z); a3 += bf2f2(u5.w);
        a0 += bf2f2(u6.x); a1 += bf2f2(u6.y); a2 += bf2f2(u6.z); a3 += bf2f2(u6.w);
        a0 += bf2f2(u7.x); a1 += bf2f2(u7.y); a2 += bf2f2(u7.z); a3 += bf2f2(u7.w);
    }
    for (; k + 3 < deg; k += 4) {
        int s0 = nb[k], s1 = nb[k + 1], s2 = nb[k + 2], s3 = nb[k + 3];
        uint4 u0 = *(const uint4*)(basep + (size_t)s0 * 128);
        uint4 u1 = *(const uint4*)(basep + (size_t)s1 * 128);
        uint4 u2 = *(const uint4*)(basep + (size_t)s2 * 128);
        uint4 u3 = *(const uint4*)(basep + (size_t)s3 * 128);
        a0 += bf2f2(u0.x); a1 += bf2f2(u0.y); a2 += bf2f2(u0.z); a3 += bf2f2(u0.w);
        a0 += bf2f2(u1.x); a1 += bf2f2(u1.y); a2 += bf2f2(u1.z); a3 += bf2f2(u1.w);
        a0 += bf2f2(u2.x); a1 += bf2f2(u2.y); a2 += bf2f2(u2.z); a3 += bf2f2(u2.w);
        a0 += bf2f2(u3.x); a1 += bf2f2(u3.y); a2 += bf2f2(u3.z); a3 += bf2f2(u3.w);
    }
    for (; k < deg; ++k) {
        int s = nb[k];
        uint4 u = *(const uint4*)(basep + (size_t)s * 128);
        a0 += bf2f2(u.x); a1 += bf2f2(u.y); a2 += bf2f2(u.z); a3 += bf2f2(u.w);
    }
    uint4 up = *(const uint4*)(qp + (size_t)g * 128 + 64 + l8 * 8);
    uint4 uq = *(const uint4*)(qp + (size_t)g * 128 + l8 * 8);
    f32x2 p0 = bf2f2(up.x), p1 = bf2f2(up.y), p2 = bf2f2(up.z), p3 = bf2f2(up.w);
    f32x2 q0 = bf2f2(uq.x), q1 = bf2f2(uq.y), q2 = bf2f2(uq.z), q3 = bf2f2(uq.w);
    float o[8];
    o[0] = (a0.x + p0.x) * inv + q0.x;
    o[1] = (a0.y + p0.y) * inv + q0.y;
    o[2] = (a1.x + p1.x) * inv + q1.x;
    o[3] = (a1.y + p1.y) * inv + q1.y;
    o[4] = (a2.x + p2.x) * inv + q2.x;
    o[5] = (a2.y + p2.y) * inv + q2.y;
    o[6] = (a3.x + p3.x) * inv + q3.x;
    o[7] = (a3.y + p3.y) * inv + q3.y;
    float* op = out + (size_t)g * 64 + l8 * 8;
    const float* bp = b2 + l8 * 8;
    *(float4*)(op + 0) = make_float4(o[0] + bp[0], o[1] + bp[1], o[2] + bp[2], o[3] + bp[3]);
    *(float4*)(op + 4) = make_float4(o[4] + bp[4], o[5] + bp[5], o[6] + bp[6], o[7] + bp[7]);
}

// ---------------- fused MFMA GEMM1+GEMM2 ----------------
__launch_bounds__(256)
__global__ void k_gemm12(const u16* __restrict__ xb, const u16* __restrict__ hnb,
                         const u16* __restrict__ W1t, const u16* __restrict__ W2t,
                         const float* __restrict__ b1, u16* __restrict__ qp, int n) {
    __shared__ u16 As[128 * 32];
    __shared__ u16 Bs[128 * 32];
    __shared__ u16 h1s[128 * H1P];
    int tid = threadIdx.x;
    int lane = tid & 63;
    int wave = tid >> 6;
    int wr = wave >> 1, wc = wave & 1;
    int row0 = blockIdx.x * 128;
    int srow = tid >> 2;
    int scol = (tid & 3) * 8;
    int m = lane & 15;
    int q = lane >> 4;

    f32x4 zero = {0.f, 0.f, 0.f, 0.f};
    f32x4 acc[4][4];
    #pragma unroll
    for (int i = 0; i < 4; ++i)
        #pragma unroll
        for (int j = 0; j < 4; ++j) acc[i][j] = zero;

    for (int kb = 0; kb < 8; ++kb) {
        const u16* Asrc = (kb < 4) ? xb : hnb;
        int kbase = (kb & 3) * 32;
        int krowB = kb * 32;
        #pragma unroll
        for (int t = 0; t < 2; ++t) {
            int gr = row0 + t * 64 + srow;
            if (gr >= n) gr = n - 1;
            GLDS16(Asrc + (size_t)gr * 128 + kbase + scol, As + t * 2048 + wave * 512);
        }
        #pragma unroll
        for (int t = 0; t < 2; ++t) {
            int nn = t * 64 + srow;
            GLDS16(W1t + (size_t)nn * 256 + krowB + scol, Bs + t * 2048 + wave * 512);
        }
        __syncthreads();
        #pragma unroll
        for (int i = 0; i < 4; ++i) {
            short8 a = *(const short8*)&As[(wr * 64 + i * 16 + m) * 32 + q * 8];
            #pragma unroll
            for (int j = 0; j < 4; ++j) {
                short8 b = *(const short8*)&Bs[(wc * 64 + j * 16 + m) * 32 + q * 8];
                acc[i][j] = __builtin_amdgcn_mfma_f32_16x16x32_bf16(a, b, acc[i][j], 0, 0, 0);
            }
        }
        __syncthreads();
    }
    #pragma unroll
    for (int i = 0; i < 4; ++i) {
        int rl = wr * 64 + i * 16 + q * 4;
        #pragma unroll
        for (int j = 0; j < 4; ++j) {
            int col = wc * 64 + j * 16 + m;
            float bias = b1[col];
            #pragma unroll
            for (int r = 0; r < 4; ++r)
                h1s[(rl + r) * H1P + col] = f2bf(fmaxf(acc[i][j][r] + bias, 0.f));
        }
    }
    #pragma unroll
    for (int i = 0; i < 4; ++i)
        #pragma unroll
        for (int j = 0; j < 4; ++j) acc[i][j] = zero;
    __syncthreads();

    for (int kb = 0; kb < 4; ++kb) {
        int kbase = kb * 32;
        #pragma unroll
        for (int t = 0; t < 2; ++t) {
            int nn = t * 64 + srow;
            GLDS16(W2t + (size_t)nn * 128 + kbase + scol, Bs + t * 2048 + wave * 512);
        }
        __syncthreads();
        #pragma unroll
        for (int i = 0; i < 4; ++i) {
            short8 a = *(const short8*)&h1s[(wr * 64 + i * 16 + m) * H1P + kbase + q * 8];
            #pragma unroll
            for (int j = 0; j < 4; ++j) {
                short8 b = *(const short8*)&Bs[(wc * 64 + j * 16 + m) * 32 + q * 8];
                acc[i][j] = __builtin_amdgcn_mfma_f32_16x16x32_bf16(a, b, acc[i][j], 0, 0, 0);
            }
        }
        __syncthreads();
    }
    #pragma unroll
    for (int i = 0; i < 4; ++i) {
        int grow = row0 + wr * 64 + i * 16 + q * 4;
        #pragma unroll
        for (int j = 0; j < 4; ++j) {
            int col = wc * 64 + j * 16 + m;
            #pragma unroll
            for (int r = 0; r < 4; ++r) {
                int gr = grow + r;
                if (gr < n) qp[(size_t)gr * 128 + col] = f2bf(acc[i][j][r]);
            }
        }
    }
}

extern "C" void kernel_launch(void* const* d_in, const int* in_sizes, int n_in,
                              void* d_out, int out_size, void* d_ws, size_t ws_size,
                              hipStream_t stream) {
    const float* x   = (const float*)d_in[0];
    const int*   src = (const int*)d_in[1];
    const int*   dst = (const int*)d_in[2];
    const float* Ws1 = (const float*)d_in[3];
    const float* Wn1 = (const float*)d_in[4];
    const float* b1  = (const float*)d_in[5];
    const float* Ws2 = (const float*)d_in[6];
    const float* Wn2 = (const float*)d_in[7];
    const float* b2  = (const float*)d_in[8];
    int n = in_sizes[0] / D_IN;
    int e = in_sizes[1];
    int nblk = (n + 1023) / 1024;     // <= 128 for n <= 131072

    char* ws = (char*)d_ws;
    size_t off = 0;
    int* deg  = (int*)(ws + off); off = align_up(off + (size_t)n * 4, 256);
    int* bsum = (int*)(ws + off); off = align_up(off + 128 * 4, 256);
    int* rs   = (int*)(ws + off); off = align_up(off + (size_t)(n + 1) * 4, 256);
    int* cur  = (int*)(ws + off); off = align_up(off + (size_t)n * 4, 256);
    int* csr  = (int*)(ws + off); off = align_up(off + (size_t)e * 4, 256);
    u16* xb   = (u16*)(ws + off); off = align_up(off + (size_t)n * 128 * 2, 256);
    unsigned int* xf8 = (unsigned int*)(ws + off); off = align_up(off + (size_t)n * 128, 256);
    u16* hnb  = (u16*)(ws + off); off = align_up(off + (size_t)n * 128 * 2, 256);
    u16* qp   = (u16*)(ws + off); off = align_up(off + (size_t)n * 128 * 2, 256);
    u16* W1t  = (u16*)(ws + off); off = align_up(off + (size_t)128 * 256 * 2, 256);
    u16* W2t  = (u16*)(ws + off); off = align_up(off + (size_t)128 * 128 * 2, 256);
    float* outp = (float*)d_out;

    const int B = 256;
    int aggGrid = (int)(((size_t)n * 8 + B - 1) / B);
    hipMemsetAsync(deg, 0, (size_t)n * 4, stream);
    k_prep<<<(n * 32 + B - 1) / B, B, 0, stream>>>(x, xb, xf8, n * 32,
                                                   Ws1, Wn1, Ws2, Wn2, W1t, W2t,
                                                   dst, deg, e);
    k_scan1<<<nblk, 256, 0, stream>>>(deg, bsum, n);
    k_rs<<<(n + B - 1) / B, B, 0, stream>>>(deg, bsum, rs, cur, n, e, nblk);
    k_place<<<(e + B - 1) / B, B, 0, stream>>>(src, dst, cur, csr, e);
    k_agg1<<<aggGrid, B, 0, stream>>>((const u8*)xf8, xb, rs, csr, hnb, n);
    k_gemm12<<<(n + 127) / 128, 256, 0, stream>>>(xb, hnb, W1t, W2t, b1, qp, n);
    k_agg2<<<aggGrid, B, 0, stream>>>(qp, rs, csr, b2, outp, n);
}

// Round 6
// 227.678 us; speedup vs baseline: 1.3108x; 1.3108x over previous
//
#include <hip/hip_runtime.h>

#define D_IN 128
#define BSH 7              // nodes per bucket = 128
#define NW  256            // binning workgroups (256 = one per CU)
#define H1P 136            // padded LDS pitch for h1 tile (bf16 elems)
#define SLICE 2048         // LDS pairs-slice capacity in k_bucket

#if defined(__has_builtin)
#if __has_builtin(__builtin_amdgcn_cvt_pk_f32_fp8)
#define HAVE_FP8 1
#endif
#endif
#ifndef HAVE_FP8
#define HAVE_FP8 0
#endif

typedef unsigned short u16;
typedef unsigned char u8;
typedef __attribute__((ext_vector_type(8))) short short8;
typedef __attribute__((ext_vector_type(4))) float f32x4;
typedef __attribute__((ext_vector_type(2))) float f32x2;

static inline size_t align_up(size_t v, size_t a) { return (v + a - 1) & ~(a - 1); }

__device__ inline u16 f2bf(float f) {
    union { float f; unsigned int u; } c; c.f = f;
    unsigned int u = c.u;
    return (u16)((u + 0x7fffu + ((u >> 16) & 1u)) >> 16);   // RNE
}
__device__ inline unsigned int packbf2(float lo, float hi) {
    return (unsigned int)f2bf(lo) | ((unsigned int)f2bf(hi) << 16);
}
__device__ inline f32x2 bf2f2(unsigned int u) {
    union { unsigned int u; float f; } lo, hi;
    lo.u = u << 16;
    hi.u = u & 0xffff0000u;
    f32x2 r; r.x = lo.f; r.y = hi.f;
    return r;
}
// f32 -> OCP e4m3fn (RNE, saturate to 448, denormal-correct)
__device__ inline unsigned int f2fp8(float f) {
    float m = fabsf(f);
    m = fminf(m, 448.0f);
    unsigned int s = (__float_as_uint(f) >> 31) << 7;
    if (m < 0.015625f) {                       // < 2^-6 : denormal codes 0..7 (and 8 on round-up)
        int c = (int)rintf(m * 512.0f);
        return s | (unsigned int)c;
    }
    unsigned int au = __float_as_uint(m);
    au += 0x7FFFF + ((au >> 20) & 1);          // RNE to 3 mantissa bits
    int e = (int)(au >> 23) - 127;
    int mant = (int)(au >> 20) & 7;
    int code = ((e + 7) << 3) | mant;
    if (code > 0x7E) code = 0x7E;              // clamp to 448
    return s | (unsigned int)code;
}
// 2 packed OCP e4m3fn -> f32x2; HI selects bytes 2,3 vs 0,1 (compile-time constant!)
template <bool HI>
__device__ inline f32x2 cvt2(unsigned int w) {
#if HAVE_FP8
    return __builtin_amdgcn_cvt_pk_f32_fp8(w, HI);
#else
    unsigned int b0 = (w >> (HI ? 16 : 0)) & 0xff;
    unsigned int b1 = (w >> (HI ? 24 : 8)) & 0xff;
    float v0, v1;
    {
        int e = (b0 >> 3) & 0xF, m = b0 & 7;
        v0 = e ? __builtin_ldexpf((float)(8 + m), e - 10) : __builtin_ldexpf((float)m, -9);
        if (b0 & 0x80) v0 = -v0;
    }
    {
        int e = (b1 >> 3) & 0xF, m = b1 & 7;
        v1 = e ? __builtin_ldexpf((float)(8 + m), e - 10) : __builtin_ldexpf((float)m, -9);
        if (b1 & 0x80) v1 = -v1;
    }
    f32x2 r; r.x = v0; r.y = v1;
    return r;
#endif
}

#define GLDS16(gp, lp) \
    __builtin_amdgcn_global_load_lds((const __attribute__((address_space(1))) void*)(gp), \
                                     (__attribute__((address_space(3))) void*)(lp), 16, 0, 0)

// ---------------- prep: cast x->bf16 + x->fp8 + pack weights + per-WG bucket hist ----------------
__global__ void k_prep(const float* __restrict__ x, u16* __restrict__ xb,
                       unsigned int* __restrict__ xf8, int total4,
                       const float* __restrict__ Ws1, const float* __restrict__ Wn1,
                       const float* __restrict__ Ws2, const float* __restrict__ Wn2,
                       u16* __restrict__ W1t, u16* __restrict__ W2t,
                       const int* __restrict__ dst, int* __restrict__ table,
                       int e, int NB, int chunk) {
    __shared__ int h[1024];
    int t = threadIdx.x;
    int i = blockIdx.x * blockDim.x + t;
    if (i < total4) {
        float4 v = ((const float4*)x)[i];
        uint2 o;
        o.x = packbf2(v.x, v.y);
        o.y = packbf2(v.z, v.w);
        *(uint2*)&xb[(size_t)i * 4] = o;
        xf8[i] = f2fp8(v.x) | (f2fp8(v.y) << 8) | (f2fp8(v.z) << 16) | (f2fp8(v.w) << 24);
    }
    if (i < 128 * 256) {
        int nn = i >> 8, kk = i & 255;
        float v = (kk < 128) ? Ws1[kk * 128 + nn] : Wn1[(kk - 128) * 128 + nn];
        W1t[i] = f2bf(v);
    }
    if (i < 128 * 128) {
        int nn = i >> 7, kk = i & 127;
        float v = (nn < 64) ? Ws2[kk * 64 + nn] : Wn2[kk * 64 + (nn - 64)];
        W2t[i] = f2bf(v);
    }
    int w = blockIdx.x;
    if (w < NW) {
        for (int j = t; j < 1024; j += 256) h[j] = 0;
        __syncthreads();
        int lo = w * chunk;
        int hi = lo + chunk; if (hi > e) hi = e;
        for (int k = lo + t; k < hi; k += 256)
            atomicAdd(&h[dst[k] >> BSH], 1);
        __syncthreads();
        for (int b = t; b < NB; b += 256)
            table[b * NW + w] = h[b];
    }
}

// ---------------- scan 1: per-block (1024) exclusive scan in place + block sums ----------------
__global__ void k_scan1(int* __restrict__ a, int* __restrict__ bsum, int T) {
    __shared__ int sd[256];
    int t = threadIdx.x;
    int base = blockIdx.x * 1024 + t * 4;
    int v[4]; int s = 0;
    #pragma unroll
    for (int j = 0; j < 4; ++j) { v[j] = (base + j < T) ? a[base + j] : 0; s += v[j]; }
    sd[t] = s;
    __syncthreads();
    #pragma unroll
    for (int off = 1; off < 256; off <<= 1) {
        int x = (t >= off) ? sd[t - off] : 0;
        __syncthreads();
        sd[t] += x;
        __syncthreads();
    }
    int run = sd[t] - s;
    #pragma unroll
    for (int j = 0; j < 4; ++j) {
        if (base + j < T) a[base + j] = run;
        run += v[j];
    }
    if (t == 255) bsum[blockIdx.x] = sd[255];
}

// ---------------- place pairs at private offsets (local bsum scan; LDS cursors) ----------------
__global__ void k_wplace(const int* __restrict__ src, const int* __restrict__ dst,
                         const int* __restrict__ table, const int* __restrict__ bsum,
                         unsigned int* __restrict__ pairs,
                         int e, int NB, int chunk, int nblk) {
    __shared__ int cur[1024];
    __shared__ int bscan[256];
    int w = blockIdx.x;
    int t = threadIdx.x;
    int own = (t < nblk) ? bsum[t] : 0;
    bscan[t] = own;
    __syncthreads();
    #pragma unroll
    for (int off = 1; off < 256; off <<= 1) {
        int v = (t >= off) ? bscan[t - off] : 0;
        __syncthreads();
        bscan[t] += v;
        __syncthreads();
    }
    bscan[t] -= own;   // exclusive
    __syncthreads();
    for (int b = t; b < NB; b += 256) {
        int idx = b * NW + w;
        cur[b] = table[idx] + bscan[idx >> 10];
    }
    __syncthreads();
    int lo = w * chunk;
    int hi = lo + chunk; if (hi > e) hi = e;
    for (int i = lo + t; i < hi; i += 256) {
        int d = dst[i];
        int p = atomicAdd(&cur[d >> BSH], 1);
        pairs[p] = ((unsigned int)src[i] << BSH) | (unsigned int)(d & 127);
    }
}

// ---------------- per-bucket: LDS slice, degree+scan, write rs[], place CSR ----------------
__global__ void k_bucket(const unsigned int* __restrict__ pairs, const int* __restrict__ table,
                         const int* __restrict__ bsum,
                         int* __restrict__ rs, int* __restrict__ csr,
                         int n, int e, int NB, int nblk) {
    __shared__ int sdeg[128];
    __shared__ int stmp[128];
    __shared__ int scur[128];
    __shared__ int bscan[256];
    __shared__ unsigned int ps[SLICE];
    int b = blockIdx.x;
    int t = threadIdx.x;
    int node0 = b << BSH;
    int own = (t < nblk) ? bsum[t] : 0;
    bscan[t] = own;
    if (t < 128) sdeg[t] = 0;
    __syncthreads();
    #pragma unroll
    for (int off = 1; off < 256; off <<= 1) {
        int v = (t >= off) ? bscan[t - off] : 0;
        __syncthreads();
        bscan[t] += v;
        __syncthreads();
    }
    bscan[t] -= own;
    __syncthreads();
    int i0 = b * NW;
    int bstart = table[i0] + bscan[i0 >> 10];
    int bend;
    if (b + 1 < NB) {
        int i1 = (b + 1) * NW;
        bend = table[i1] + bscan[i1 >> 10];
    } else bend = e;
    int len = bend - bstart;
    bool fits = (len <= SLICE);
    if (fits) {
        for (int i = t; i < len; i += 256) {
            unsigned int u = pairs[bstart + i];
            ps[i] = u;
            atomicAdd(&sdeg[u & 127], 1);
        }
    } else {
        for (int i = bstart + t; i < bend; i += 256)
            atomicAdd(&sdeg[pairs[i] & 127], 1);
    }
    __syncthreads();
    if (t < 128) stmp[t] = sdeg[t];
    __syncthreads();
    #pragma unroll
    for (int off = 1; off < 128; off <<= 1) {
        int v = (t < 128 && t >= off) ? stmp[t - off] : 0;
        __syncthreads();
        if (t < 128) stmp[t] += v;
        __syncthreads();
    }
    if (t < 128) {
        int excl = stmp[t] - sdeg[t];
        scur[t] = excl;
        int node = node0 + t;
        if (node < n) rs[node] = bstart + excl;
    }
    if (b == (int)gridDim.x - 1 && t == 0) rs[n] = e;
    __syncthreads();
    if (fits) {
        for (int i = t; i < len; i += 256) {
            unsigned int u = ps[i];
            int p = atomicAdd(&scur[u & 127], 1);
            csr[bstart + p] = (int)(u >> BSH);
        }
    } else {
        for (int i = bstart + t; i < bend; i += 256) {
            unsigned int u = pairs[i];
            int p = atomicAdd(&scur[u & 127], 1);
            csr[bstart + p] = (int)(u >> BSH);
        }
    }
}

#define ACC8(U) do { \
    a0 += cvt2<false>((U).x); a1 += cvt2<true>((U).x);  \
    a2 += cvt2<false>((U).y); a3 += cvt2<true>((U).y);  \
    a4 += cvt2<false>((U).z); a5 += cvt2<true>((U).z);  \
    a6 += cvt2<false>((U).w); a7 += cvt2<true>((U).w); } while (0)

// ---------------- layer-1 gather-aggregate: 8 lanes per node, group-serial, NO reduce ----------
// Each lane owns a private 16 B (16 fp8 feats) slice of the row; the 8-lane group walks its
// node's edge list (unroll-8 => up to 64 row-gathers in flight per wave). Zero cross-lane traffic.
__global__ void k_agg1(const u8* __restrict__ xf8, const u16* __restrict__ xb,
                       const int* __restrict__ rs, const int* __restrict__ csr,
                       u16* __restrict__ hnb, int n) {
    int g = (blockIdx.x * blockDim.x + threadIdx.x) >> 3;   // node index
    int l8 = threadIdx.x & 7;                               // 16 B feature slice
    if (g >= n) return;
    int start = rs[g];
    int deg = rs[g + 1] - start;
    float inv = 1.0f / (1.0f + (float)deg);
    const int* nb = csr + start;
    const u8* base = xf8 + l8 * 16;
    f32x2 a0 = {0.f,0.f}, a1 = {0.f,0.f}, a2 = {0.f,0.f}, a3 = {0.f,0.f};
    f32x2 a4 = {0.f,0.f}, a5 = {0.f,0.f}, a6 = {0.f,0.f}, a7 = {0.f,0.f};
    int k = 0;
    for (; k + 7 < deg; k += 8) {
        int s0 = nb[k],     s1 = nb[k + 1], s2 = nb[k + 2], s3 = nb[k + 3];
        int s4 = nb[k + 4], s5 = nb[k + 5], s6 = nb[k + 6], s7 = nb[k + 7];
        uint4 u0 = *(const uint4*)(base + (size_t)s0 * 128);
        uint4 u1 = *(const uint4*)(base + (size_t)s1 * 128);
        uint4 u2 = *(const uint4*)(base + (size_t)s2 * 128);
        uint4 u3 = *(const uint4*)(base + (size_t)s3 * 128);
        uint4 u4 = *(const uint4*)(base + (size_t)s4 * 128);
        uint4 u5 = *(const uint4*)(base + (size_t)s5 * 128);
        uint4 u6 = *(const uint4*)(base + (size_t)s6 * 128);
        uint4 u7 = *(const uint4*)(base + (size_t)s7 * 128);
        ACC8(u0); ACC8(u1); ACC8(u2); ACC8(u3);
        ACC8(u4); ACC8(u5); ACC8(u6); ACC8(u7);
    }
    for (; k + 3 < deg; k += 4) {
        int s0 = nb[k], s1 = nb[k + 1], s2 = nb[k + 2], s3 = nb[k + 3];
        uint4 u0 = *(const uint4*)(base + (size_t)s0 * 128);
        uint4 u1 = *(const uint4*)(base + (size_t)s1 * 128);
        uint4 u2 = *(const uint4*)(base + (size_t)s2 * 128);
        uint4 u3 = *(const uint4*)(base + (size_t)s3 * 128);
        ACC8(u0); ACC8(u1); ACC8(u2); ACC8(u3);
    }
    for (; k < deg; ++k) {
        int s = nb[k];
        uint4 u = *(const uint4*)(base + (size_t)s * 128);
        ACC8(u);
    }
    // self row (bf16): feats [l8*16, l8*16+16)
    uint4 s0 = *(const uint4*)(xb + (size_t)g * 128 + l8 * 16);
    uint4 s1 = *(const uint4*)(xb + (size_t)g * 128 + l8 * 16 + 8);
    a0 += bf2f2(s0.x); a1 += bf2f2(s0.y); a2 += bf2f2(s0.z); a3 += bf2f2(s0.w);
    a4 += bf2f2(s1.x); a5 += bf2f2(s1.y); a6 += bf2f2(s1.z); a7 += bf2f2(s1.w);
    uint4 o0, o1;
    o0.x = packbf2(a0.x * inv, a0.y * inv);
    o0.y = packbf2(a1.x * inv, a1.y * inv);
    o0.z = packbf2(a2.x * inv, a2.y * inv);
    o0.w = packbf2(a3.x * inv, a3.y * inv);
    o1.x = packbf2(a4.x * inv, a4.y * inv);
    o1.y = packbf2(a5.x * inv, a5.y * inv);
    o1.z = packbf2(a6.x * inv, a6.y * inv);
    o1.w = packbf2(a7.x * inv, a7.y * inv);
    *(uint4*)(hnb + (size_t)g * 128 + l8 * 16) = o0;
    *(uint4*)(hnb + (size_t)g * 128 + l8 * 16 + 8) = o1;
}

// ---------------- layer-2 gather-aggregate + epilogue: 8 lanes per node, NO reduce ------------
__global__ void k_agg2(const u16* __restrict__ qp, const int* __restrict__ rs,
                       const int* __restrict__ csr, const float* __restrict__ b2,
                       float* __restrict__ out, int n) {
    int g = (blockIdx.x * blockDim.x + threadIdx.x) >> 3;
    int l8 = threadIdx.x & 7;         // 8 bf16 feats (16 B) of the p-half
    if (g >= n) return;
    int start = rs[g];
    int deg = rs[g + 1] - start;
    float inv = 1.0f / (1.0f + (float)deg);
    const int* nb = csr + start;
    const u16* basep = qp + 64 + l8 * 8;
    f32x2 a0 = {0.f,0.f}, a1 = {0.f,0.f}, a2 = {0.f,0.f}, a3 = {0.f,0.f};
    int k = 0;
    for (; k + 7 < deg; k += 8) {
        int s0 = nb[k],     s1 = nb[k + 1], s2 = nb[k + 2], s3 = nb[k + 3];
        int s4 = nb[k + 4], s5 = nb[k + 5], s6 = nb[k + 6], s7 = nb[k + 7];
        uint4 u0 = *(const uint4*)(basep + (size_t)s0 * 128);
        uint4 u1 = *(const uint4*)(basep + (size_t)s1 * 128);
        uint4 u2 = *(const uint4*)(basep + (size_t)s2 * 128);
        uint4 u3 = *(const uint4*)(basep + (size_t)s3 * 128);
        uint4 u4 = *(const uint4*)(basep + (size_t)s4 * 128);
        uint4 u5 = *(const uint4*)(basep + (size_t)s5 * 128);
        uint4 u6 = *(const uint4*)(basep + (size_t)s6 * 128);
        uint4 u7 = *(const uint4*)(basep + (size_t)s7 * 128);
        a0 += bf2f2(u0.x); a1 += bf2f2(u0.y); a2 += bf2f2(u0.z); a3 += bf2f2(u0.w);
        a0 += bf2f2(u1.x); a1 += bf2f2(u1.y); a2 += bf2f2(u1.z); a3 += bf2f2(u1.w);
        a0 += bf2f2(u2.x); a1 += bf2f2(u2.y); a2 += bf2f2(u2.z); a3 += bf2f2(u2.w);
        a0 += bf2f2(u3.x); a1 += bf2f2(u3.y); a2 += bf2f2(u3.z); a3 += bf2f2(u3.w);
        a0 += bf2f2(u4.x); a1 += bf2f2(u4.y); a2 += bf2f2(u4.z); a3 += bf2f2(u4.w);
        a0 += bf2f2(u5.x); a1 += bf2f2(u5.y); a2 += bf2f2(u5.z); a3 += bf2f2(u5.w);
        a0 += bf2f2(u6.x); a1 += bf2f2(u6.y); a2 += bf2f2(u6.z); a3 += bf2f2(u6.w);
        a0 += bf2f2(u7.x); a1 += bf2f2(u7.y); a2 += bf2f2(u7.z); a3 += bf2f2(u7.w);
    }
    for (; k + 3 < deg; k += 4) {
        int s0 = nb[k], s1 = nb[k + 1], s2 = nb[k + 2], s3 = nb[k + 3];
        uint4 u0 = *(const uint4*)(basep + (size_t)s0 * 128);
        uint4 u1 = *(const uint4*)(basep + (size_t)s1 * 128);
        uint4 u2 = *(const uint4*)(basep + (size_t)s2 * 128);
        uint4 u3 = *(const uint4*)(basep + (size_t)s3 * 128);
        a0 += bf2f2(u0.x); a1 += bf2f2(u0.y); a2 += bf2f2(u0.z); a3 += bf2f2(u0.w);
        a0 += bf2f2(u1.x); a1 += bf2f2(u1.y); a2 += bf2f2(u1.z); a3 += bf2f2(u1.w);
        a0 += bf2f2(u2.x); a1 += bf2f2(u2.y); a2 += bf2f2(u2.z); a3 += bf2f2(u2.w);
        a0 += bf2f2(u3.x); a1 += bf2f2(u3.y); a2 += bf2f2(u3.z); a3 += bf2f2(u3.w);
    }
    for (; k < deg; ++k) {
        int s = nb[k];
        uint4 u = *(const uint4*)(basep + (size_t)s * 128);
        a0 += bf2f2(u.x); a1 += bf2f2(u.y); a2 += bf2f2(u.z); a3 += bf2f2(u.w);
    }
    uint4 up = *(const uint4*)(qp + (size_t)g * 128 + 64 + l8 * 8);
    uint4 uq = *(const uint4*)(qp + (size_t)g * 128 + l8 * 8);
    f32x2 p0 = bf2f2(up.x), p1 = bf2f2(up.y), p2 = bf2f2(up.z), p3 = bf2f2(up.w);
    f32x2 q0 = bf2f2(uq.x), q1 = bf2f2(uq.y), q2 = bf2f2(uq.z), q3 = bf2f2(uq.w);
    float o[8];
    o[0] = (a0.x + p0.x) * inv + q0.x;
    o[1] = (a0.y + p0.y) * inv + q0.y;
    o[2] = (a1.x + p1.x) * inv + q1.x;
    o[3] = (a1.y + p1.y) * inv + q1.y;
    o[4] = (a2.x + p2.x) * inv + q2.x;
    o[5] = (a2.y + p2.y) * inv + q2.y;
    o[6] = (a3.x + p3.x) * inv + q3.x;
    o[7] = (a3.y + p3.y) * inv + q3.y;
    float* op = out + (size_t)g * 64 + l8 * 8;
    const float* bp = b2 + l8 * 8;
    *(float4*)(op + 0) = make_float4(o[0] + bp[0], o[1] + bp[1], o[2] + bp[2], o[3] + bp[3]);
    *(float4*)(op + 4) = make_float4(o[4] + bp[4], o[5] + bp[5], o[6] + bp[6], o[7] + bp[7]);
}

// ---------------- fused MFMA GEMM1+GEMM2 ----------------
__launch_bounds__(256)
__global__ void k_gemm12(const u16* __restrict__ xb, const u16* __restrict__ hnb,
                         const u16* __restrict__ W1t, const u16* __restrict__ W2t,
                         const float* __restrict__ b1, u16* __restrict__ qp, int n) {
    __shared__ u16 As[128 * 32];
    __shared__ u16 Bs[128 * 32];
    __shared__ u16 h1s[128 * H1P];
    int tid = threadIdx.x;
    int lane = tid & 63;
    int wave = tid >> 6;
    int wr = wave >> 1, wc = wave & 1;
    int row0 = blockIdx.x * 128;
    int srow = tid >> 2;
    int scol = (tid & 3) * 8;
    int m = lane & 15;
    int q = lane >> 4;

    f32x4 zero = {0.f, 0.f, 0.f, 0.f};
    f32x4 acc[4][4];
    #pragma unroll
    for (int i = 0; i < 4; ++i)
        #pragma unroll
        for (int j = 0; j < 4; ++j) acc[i][j] = zero;

    for (int kb = 0; kb < 8; ++kb) {
        const u16* Asrc = (kb < 4) ? xb : hnb;
        int kbase = (kb & 3) * 32;
        int krowB = kb * 32;
        #pragma unroll
        for (int t = 0; t < 2; ++t) {
            int gr = row0 + t * 64 + srow;
            if (gr >= n) gr = n - 1;
            GLDS16(Asrc + (size_t)gr * 128 + kbase + scol, As + t * 2048 + wave * 512);
        }
        #pragma unroll
        for (int t = 0; t < 2; ++t) {
            int nn = t * 64 + srow;
            GLDS16(W1t + (size_t)nn * 256 + krowB + scol, Bs + t * 2048 + wave * 512);
        }
        __syncthreads();
        #pragma unroll
        for (int i = 0; i < 4; ++i) {
            short8 a = *(const short8*)&As[(wr * 64 + i * 16 + m) * 32 + q * 8];
            #pragma unroll
            for (int j = 0; j < 4; ++j) {
                short8 b = *(const short8*)&Bs[(wc * 64 + j * 16 + m) * 32 + q * 8];
                acc[i][j] = __builtin_amdgcn_mfma_f32_16x16x32_bf16(a, b, acc[i][j], 0, 0, 0);
            }
        }
        __syncthreads();
    }
    #pragma unroll
    for (int i = 0; i < 4; ++i) {
        int rl = wr * 64 + i * 16 + q * 4;
        #pragma unroll
        for (int j = 0; j < 4; ++j) {
            int col = wc * 64 + j * 16 + m;
            float bias = b1[col];
            #pragma unroll
            for (int r = 0; r < 4; ++r)
                h1s[(rl + r) * H1P + col] = f2bf(fmaxf(acc[i][j][r] + bias, 0.f));
        }
    }
    #pragma unroll
    for (int i = 0; i < 4; ++i)
        #pragma unroll
        for (int j = 0; j < 4; ++j) acc[i][j] = zero;
    __syncthreads();

    for (int kb = 0; kb < 4; ++kb) {
        int kbase = kb * 32;
        #pragma unroll
        for (int t = 0; t < 2; ++t) {
            int nn = t * 64 + srow;
            GLDS16(W2t + (size_t)nn * 128 + kbase + scol, Bs + t * 2048 + wave * 512);
        }
        __syncthreads();
        #pragma unroll
        for (int i = 0; i < 4; ++i) {
            short8 a = *(const short8*)&h1s[(wr * 64 + i * 16 + m) * H1P + kbase + q * 8];
            #pragma unroll
            for (int j = 0; j < 4; ++j) {
                short8 b = *(const short8*)&Bs[(wc * 64 + j * 16 + m) * 32 + q * 8];
                acc[i][j] = __builtin_amdgcn_mfma_f32_16x16x32_bf16(a, b, acc[i][j], 0, 0, 0);
            }
        }
        __syncthreads();
    }
    #pragma unroll
    for (int i = 0; i < 4; ++i) {
        int grow = row0 + wr * 64 + i * 16 + q * 4;
        #pragma unroll
        for (int j = 0; j < 4; ++j) {
            int col = wc * 64 + j * 16 + m;
            #pragma unroll
            for (int r = 0; r < 4; ++r) {
                int gr = grow + r;
                if (gr < n) qp[(size_t)gr * 128 + col] = f2bf(acc[i][j][r]);
            }
        }
    }
}

extern "C" void kernel_launch(void* const* d_in, const int* in_sizes, int n_in,
                              void* d_out, int out_size, void* d_ws, size_t ws_size,
                              hipStream_t stream) {
    const float* x   = (const float*)d_in[0];
    const int*   src = (const int*)d_in[1];
    const int*   dst = (const int*)d_in[2];
    const float* Ws1 = (const float*)d_in[3];
    const float* Wn1 = (const float*)d_in[4];
    const float* b1  = (const float*)d_in[5];
    const float* Ws2 = (const float*)d_in[6];
    const float* Wn2 = (const float*)d_in[7];
    const float* b2  = (const float*)d_in[8];
    int n = in_sizes[0] / D_IN;
    int e = in_sizes[1];
    int NB = (n + 127) >> BSH;
    int T = NB * NW;
    int chunk = (e + NW - 1) / NW;
    int nblk = (T + 1023) / 1024;     // <= 256 for n <= 131072 at NW=256

    char* ws = (char*)d_ws;
    size_t off = 0;
    int* table = (int*)(ws + off); off = align_up(off + (size_t)T * 4, 256);
    int* bsum  = (int*)(ws + off); off = align_up(off + 256 * 4, 256);
    unsigned int* pairs = (unsigned int*)(ws + off); off = align_up(off + (size_t)e * 4, 256);
    int* rs    = (int*)(ws + off); off = align_up(off + (size_t)(n + 1) * 4, 256);
    int* csr   = (int*)(ws + off); off = align_up(off + (size_t)e * 4, 256);
    u16* xb    = (u16*)(ws + off); off = align_up(off + (size_t)n * 128 * 2, 256);
    unsigned int* xf8 = (unsigned int*)(ws + off); off = align_up(off + (size_t)n * 128, 256);
    u16* hnb   = (u16*)(ws + off); off = align_up(off + (size_t)n * 128 * 2, 256);
    u16* qp    = (u16*)(ws + off); off = align_up(off + (size_t)n * 128 * 2, 256);
    u16* W1t   = (u16*)(ws + off); off = align_up(off + (size_t)128 * 256 * 2, 256);
    u16* W2t   = (u16*)(ws + off); off = align_up(off + (size_t)128 * 128 * 2, 256);
    float* outp = (float*)d_out;

    const int B = 256;
    int aggGrid = (int)(((size_t)n * 8 + B - 1) / B);
    k_prep<<<(n * 32 + B - 1) / B, B, 0, stream>>>(x, xb, xf8, n * 32,
                                                   Ws1, Wn1, Ws2, Wn2, W1t, W2t,
                                                   dst, table, e, NB, chunk);
    k_scan1<<<nblk, 256, 0, stream>>>(table, bsum, T);
    k_wplace<<<NW, B, 0, stream>>>(src, dst, table, bsum, pairs, e, NB, chunk, nblk);
    k_bucket<<<NB, 256, 0, stream>>>(pairs, table, bsum, rs, csr, n, e, NB, nblk);
    k_agg1<<<aggGrid, B, 0, stream>>>((const u8*)xf8, xb, rs, csr, hnb, n);
    k_gemm12<<<(n + 127) / 128, 256, 0, stream>>>(xb, hnb, W1t, W2t, b1, qp, n);
    k_agg2<<<aggGrid, B, 0, stream>>>(qp, rs, csr, b2, outp, n);
}